// Round 13
// baseline (371.704 us; speedup 1.0000x reference)
//
#include <hip/hip_runtime.h>

#define NNODES 65536
#define CC 128
#define NEL 10
#define BN 16
#define NT 64

#define INV_SQ2f 0.70710678118654752440f
#define INV_SQ6f 0.40824829046386301637f
#define INV_2Cf  0.0625f               /* 1/sqrt(256) */
#define INV_Cf   0.08838834764831845f  /* 1/sqrt(128) */
#define S16f 0.25f
#define S64f 0.125f

#define WS_FRAGS 312

// Compiler-only memory fence: zero instructions, prevents TBAA-based
// reordering of LDS writes/reads across phase boundaries. Hardware LDS is
// in-order per wave, so this is ALL the sync a 1-wave block needs.
#define CFENCE() asm volatile("" ::: "memory")

typedef __attribute__((ext_vector_type(8))) short s16x8;
typedef __attribute__((ext_vector_type(4))) float f32x4;
#define MFMA16(a, b, c) __builtin_amdgcn_mfma_f32_16x16x32_bf16((a), (b), (c), 0, 0, 0)

union U8 { unsigned short u[8]; s16x8 s; };

__device__ __forceinline__ unsigned short bf16rne(float x) {
    unsigned int u = __float_as_uint(x);
    return (unsigned short)((u + 0x7FFFu + ((u >> 16) & 1u)) >> 16);
}
__device__ __forceinline__ float bf2f(unsigned short h) {
    return __uint_as_float(((unsigned int)h) << 16);
}
__device__ __forceinline__ unsigned int packbf(float a, float b) {
    return (unsigned int)bf16rne(a) | (((unsigned int)bf16rne(b)) << 16);
}
__device__ __forceinline__ float siluf(float x) {
    return x * (1.0f / (1.0f + __expf(-x)));
}

// ---------------- weight fragment prep (one-shot, 312 frags) ----------------
extern "C" __global__ void prep_frags(
    const float* __restrict__ WC1, const float* __restrict__ WC2,
    const float* __restrict__ WC3, const float* __restrict__ WB1,
    const float* __restrict__ WB2, const float* __restrict__ WB3,
    const float* __restrict__ WC4, const float* __restrict__ WB4,
    const float* __restrict__ WL0, const float* __restrict__ WO0,
    const float* __restrict__ WL1, const float* __restrict__ WO1,
    unsigned short* __restrict__ wsb)
{
    const int b = blockIdx.x;
    const int l = threadIdx.x;
    const float* W; int K, N, nKS, base; float sc;
    if      (b <  4) { W = WC1; K = 16;  N = 64;  nKS = 1; base = 0;   sc = S16f; }
    else if (b < 12) { W = WC2; K = 64;  N = 64;  nKS = 2; base = 4;   sc = S64f; }
    else if (b < 20) { W = WC3; K = 64;  N = 64;  nKS = 2; base = 12;  sc = S64f; }
    else if (b < 24) { W = WB1; K = 16;  N = 64;  nKS = 1; base = 20;  sc = S16f; }
    else if (b < 32) { W = WB2; K = 64;  N = 64;  nKS = 2; base = 24;  sc = S64f; }
    else if (b < 40) { W = WB3; K = 64;  N = 64;  nKS = 2; base = 32;  sc = S64f; }
    else if (b < 104){ W = WC4; K = 64;  N = 512; nKS = 2; base = 40;  sc = S64f; }
    else if (b < 120){ W = WB4; K = 64;  N = 128; nKS = 2; base = 104; sc = S64f; }
    else if (b < 184){ W = WL0; K = 256; N = 128; nKS = 8; base = 120; sc = INV_2Cf; }
    else if (b < 216){ W = WO0; K = 128; N = 128; nKS = 4; base = 184; sc = INV_Cf; }
    else if (b < 280){ W = WL1; K = 256; N = 128; nKS = 8; base = 216; sc = INV_2Cf; }
    else             { W = WO1; K = 128; N = 128; nKS = 4; base = 280; sc = INV_Cf; }
    const int f  = b - base;
    const int nt = f / nKS, ks = f % nKS;
    const int n  = nt * 16 + (l & 15);
    const int k0 = ks * 32 + (l >> 4) * 8;
    U8 v;
    #pragma unroll
    for (int j = 0; j < 8; ++j) {
        const int k = k0 + j;
        const float x = (k < K) ? W[(size_t)k * N + n] * sc : 0.0f;
        v.u[j] = bf16rne(x);
    }
    *(s16x8*)(wsb + (size_t)b * 512 + l * 8) = v.s;
}

// ---------------- helpers ----------------
__device__ __forceinline__ s16x8 ldB(const unsigned short* __restrict__ wsb, int fragidx, int lane) {
    return *(const s16x8*)(wsb + ((size_t)fragidx << 9) + lane * 8);
}
__device__ __forceinline__ s16x8 ldA136(const unsigned short* X, int row, int ks, int gq) {
    return *(const s16x8*)(X + row * 136 + ks * 32 + gq * 8);
}
__device__ __forceinline__ s16x8 ldA72(const unsigned short* X, int row, int ks, int gq) {
    return *(const s16x8*)(X + row * 72 + ks * 32 + gq * 8);
}

// ---------------- main kernel: ONE WAVE per block, ZERO barriers ----------------
// BN=16 nodes/block, 64 threads. All LDS is wave-private; hardware executes a
// wave's ds ops in order, so correctness only needs the COMPILER to preserve
// program order across mixed-type accesses -> CFENCE() at phase boundaries
// (R12's NaN was TBAA reordering uint writes vs short reads, zero-cost fix).
extern "C" __global__ void __launch_bounds__(NT)
epb_wave(const float* __restrict__ Sin, const float* __restrict__ Vin,
         const float* __restrict__ SCp, const float* __restrict__ ATT,
         const float* __restrict__ INVF, const float* __restrict__ MNA,
         const float* __restrict__ MLEN, const float* __restrict__ WSp,
         const float* __restrict__ WVp, const float* __restrict__ ESC,
         const unsigned short* __restrict__ wsb, float* __restrict__ OUT)
{
    extern __shared__ char smem[];
    unsigned short* B1 = (unsigned short*)smem;          // Hc1/Hc3 -> os -> bv
    unsigned short* B2 = B1 + 2176;                      // Hb1/Hb3 -> gate (persists)
    unsigned short* B3 = B2 + 2176;                      // Hc2 -> vy -> m1 -> b
    unsigned short* B4 = B3 + 2176;                      // Hb2 -> m0 -> a2 -> gv
    float* y0f = (float*)(smem + 4 * 4352);              // [16]
    float* y1f = y0f + 16;                               // [16][3]
    float* etf = y1f + 48;                               // [16]

    const int lane = threadIdx.x;
    const int cl   = lane & 15;
    const int gq   = lane >> 4;
    const int n0   = blockIdx.x * BN;
    const f32x4 Z4 = {0.f, 0.f, 0.f, 0.f};

    // ---- inv A-fragment (rows = cl, K=16 padded to 32) ----
    U8 invu;
    if (gq < 2) {
        const float* ip = INVF + (size_t)(n0 + cl) * 16 + gq * 8;
        #pragma unroll
        for (int j = 0; j < 8; ++j) invu.u[j] = bf16rne(ip[j]);
    } else {
        #pragma unroll
        for (int j = 0; j < 8; ++j) invu.u[j] = 0;
    }

    // ---- per-node smalls (lanes 0-15) ----
    if (lane < BN) {
        const int gn = n0 + lane;
        y0f[lane] = MNA[gn * 4 + 0];
        y1f[lane * 3 + 0] = MNA[gn * 4 + 1];
        y1f[lane * 3 + 1] = MNA[gn * 4 + 2];
        y1f[lane * 3 + 2] = MNA[gn * 4 + 3];
        etf[lane] = 1.0f - __expf(-ESC[0] * MLEN[gn]);
    }
    CFENCE();

    // ---- MLP L1: inv @ WC1 -> B1, inv @ WB1 -> B2 ([16][72] layout) ----
    #pragma unroll
    for (int mt = 0; mt < 4; ++mt) {
        const f32x4 c = MFMA16(invu.s, ldB(wsb, 0 + mt, lane), Z4);
        const f32x4 b = MFMA16(invu.s, ldB(wsb, 20 + mt, lane), Z4);
        #pragma unroll
        for (int r = 0; r < 4; ++r) {
            const int rw = gq * 4 + r;
            B1[rw * 72 + mt * 16 + cl] = bf16rne(siluf(c[r]));
            B2[rw * 72 + mt * 16 + cl] = bf16rne(siluf(b[r]));
        }
    }
    CFENCE();
    // ---- L2: B1 -> B3, B2 -> B4 ----
    #pragma unroll
    for (int mt = 0; mt < 4; ++mt) {
        f32x4 c = Z4, b = Z4;
        #pragma unroll
        for (int ks = 0; ks < 2; ++ks) {
            c = MFMA16(ldA72(B1, cl, ks, gq), ldB(wsb, 4 + mt * 2 + ks, lane), c);
            b = MFMA16(ldA72(B2, cl, ks, gq), ldB(wsb, 24 + mt * 2 + ks, lane), b);
        }
        #pragma unroll
        for (int r = 0; r < 4; ++r) {
            const int rw = gq * 4 + r;
            B3[rw * 72 + mt * 16 + cl] = bf16rne(siluf(c[r]));
            B4[rw * 72 + mt * 16 + cl] = bf16rne(siluf(b[r]));
        }
    }
    CFENCE();
    // ---- L3: B3 -> B1, B4 -> B2 ----
    #pragma unroll
    for (int mt = 0; mt < 4; ++mt) {
        f32x4 c = Z4, b = Z4;
        #pragma unroll
        for (int ks = 0; ks < 2; ++ks) {
            c = MFMA16(ldA72(B3, cl, ks, gq), ldB(wsb, 12 + mt * 2 + ks, lane), c);
            b = MFMA16(ldA72(B4, cl, ks, gq), ldB(wsb, 32 + mt * 2 + ks, lane), b);
        }
        #pragma unroll
        for (int r = 0; r < 4; ++r) {
            const int rw = gq * 4 + r;
            B1[rw * 72 + mt * 16 + cl] = bf16rne(siluf(c[r]));
            B2[rw * 72 + mt * 16 + cl] = bf16rne(siluf(b[r]));
        }
    }
    CFENCE();

    // ---- h3 -> regs; ob for all 8 tiles ----
    s16x8 h3c[2], h3b[2];
    #pragma unroll
    for (int ks = 0; ks < 2; ++ks) {
        h3c[ks] = ldA72(B1, cl, ks, gq);
        h3b[ks] = ldA72(B2, cl, ks, gq);
    }
    CFENCE();   // h3 ds_reads must not sink below P2's overwrites of B1/B2
    f32x4 obacc[8];
    #pragma unroll
    for (int T = 0; T < 8; ++T) {
        const s16x8 f0 = ldB(wsb, 104 + T * 2 + 0, lane);
        const s16x8 f1 = ldB(wsb, 104 + T * 2 + 1, lane);
        obacc[T] = MFMA16(h3b[1], f1, MFMA16(h3b[0], f0, Z4));
    }

    // ---- P2: out_s->B1, gate->B2, vy->B3 ([16][136]); v packed in regs ----
    unsigned int vpack[3][16];
    {
        const int row = lane >> 2;
        const int c0  = (lane & 3) << 5;
        const size_t gn = (size_t)(n0 + row);
        const float4 mna = *(const float4*)(MNA + gn * 4);
        const float y10 = mna.y, y11 = mna.z, y12 = mna.w;
        int e = 0;
        #pragma unroll
        for (int k = 0; k < NEL; ++k)
            if (ATT[gn * NEL + k] > 0.5f) e = k;
        const float* sp  = Sin + gn * CC + c0;
        const float* vp  = Vin + (gn * CC + c0) * 3;
        const float* wsp = WSp + ((size_t)e * 5) * CC + c0;
        const float* wvp = WVp + ((size_t)e * 4) * CC + c0;
        unsigned int* B1d = (unsigned int*)B1;
        unsigned int* B2d = (unsigned int*)B2;
        unsigned int* B3d = (unsigned int*)B3;
        const int dbase = row * 68 + (c0 >> 1);
        #pragma unroll
        for (int jp = 0; jp < 16; ++jp) {
            const int c = 2 * jp;
            const float2 s2 = *(const float2*)(sp + c);
            const float2 va = *(const float2*)(vp + 3 * c);
            const float2 vb = *(const float2*)(vp + 3 * c + 2);
            const float2 vc = *(const float2*)(vp + 3 * c + 4);
            vpack[0][jp] = packbf(va.x, vb.y);
            vpack[1][jp] = packbf(va.y, vc.x);
            vpack[2][jp] = packbf(vb.x, vc.y);
            const float vv0 = va.x * va.x + va.y * va.y + vb.x * vb.x;
            const float vv1 = vb.y * vb.y + vc.x * vc.x + vc.y * vc.y;
            const float vy0 = va.x * y10 + va.y * y11 + vb.x * y12;
            const float vy1 = vb.y * y10 + vc.x * y11 + vc.y * y12;
            const float2 p0 = *(const float2*)(wsp + 0 * CC + c);
            const float2 p1 = *(const float2*)(wsp + 1 * CC + c);
            const float2 p2 = *(const float2*)(wsp + 2 * CC + c);
            const float2 p3 = *(const float2*)(wsp + 3 * CC + c);
            const float2 p4 = *(const float2*)(wsp + 4 * CC + c);
            const float2 q0 = *(const float2*)(wvp + 0 * CC + c);
            const float2 q1 = *(const float2*)(wvp + 1 * CC + c);
            const float2 q2 = *(const float2*)(wvp + 2 * CC + c);
            const float2 q3 = *(const float2*)(wvp + 3 * CC + c);
            const float s0 = s2.x, s1 = s2.y;
            const float ss0 = s0 * s0, ss1 = s1 * s1;
            const float os0 = p0.x * s0 + p1.x * ss0 + p2.x * vv0 + p3.x * (ss0 * s0) + p4.x * (s0 * vv0);
            const float os1 = p0.y * s1 + p1.y * ss1 + p2.y * vv1 + p3.y * (ss1 * s1) + p4.y * (s1 * vv1);
            const float gt0 = q0.x + q1.x * s0 + q2.x * ss0 + q3.x * vv0;
            const float gt1 = q0.y + q1.y * s1 + q2.y * ss1 + q3.y * vv1;
            B1d[dbase + jp] = packbf(os0, os1);
            B2d[dbase + jp] = packbf(gt0, gt1);
            B3d[dbase + jp] = packbf(vy0, vy1);
        }
    }
    CFENCE();   // uint writes -> short reads below (TBAA hazard)

#define WCHUNK(q, T, wc)                                                       \
    {                                                                          \
        const s16x8 f0 = ldB(wsb, 40 + ((q) * 8 + (T)) * 2 + 0, lane);         \
        const s16x8 f1 = ldB(wsb, 40 + ((q) * 8 + (T)) * 2 + 1, lane);         \
        wc = MFMA16(h3c[1], f1, MFMA16(h3c[0], f0, Z4));                       \
    }

    // ---- m-phase: m0 -> B4 (over Hb2), m1 -> B3 (in place over vy) ----
    #pragma unroll
    for (int T = 0; T < 8; ++T) {
        f32x4 wc0, wc1;
        WCHUNK(0, T, wc0)
        WCHUNK(1, T, wc1)
        #pragma unroll
        for (int r = 0; r < 4; ++r) {
            const int rw = gq * 4 + r;
            const int col = T * 16 + cl;
            const float os = bf2f(B1[rw * 136 + col]);
            B4[rw * 136 + col] = bf16rne(INV_SQ2f * wc0[r] * os * y0f[rw]
                                         + etf[rw] * obacc[T][r]);
            const float gt = bf2f(B2[rw * 136 + col]);
            const float vy = bf2f(B3[rw * 136 + col]);
            B3[rw * 136 + col] = bf16rne(INV_SQ6f * wc1[r] * gt * vy);
        }
    }
    CFENCE();

    // ---- G1: msg0 = [m0|m1|os] @ [Wl0a;Wl0b;Wo0] + sc ----
    {
        f32x4 acc[8] = {Z4, Z4, Z4, Z4, Z4, Z4, Z4, Z4};
        #pragma unroll
        for (int ks = 0; ks < 12; ++ks) {
            const unsigned short* Xa = (ks < 4) ? B4 : (ks < 8) ? B3 : B1;
            const s16x8 a = ldA136(Xa, cl, ks & 3, gq);
            #pragma unroll
            for (int T = 0; T < 8; ++T) {
                const int fi = (ks < 8) ? (120 + T * 8 + ks) : (184 + T * 4 + (ks - 8));
                acc[T] = MFMA16(a, ldB(wsb, fi, lane), acc[T]);
            }
        }
        #pragma unroll
        for (int T = 0; T < 8; ++T)
            #pragma unroll
            for (int r = 0; r < 4; ++r) {
                const int rw = gq * 4 + r;
                const size_t o = (size_t)(n0 + rw) * 512 + T * 16 + cl;
                OUT[o] = acc[T][r] + SCp[o];
            }
    }
    CFENCE();   // G1 ds_reads must finish (program order) before ab overwrites

    // ---- ab-phase: a2 -> B4 (over m0, dead), b -> B3 (over m1, dead) ----
    #pragma unroll
    for (int T = 0; T < 8; ++T) {
        f32x4 wc2, wc3;
        WCHUNK(2, T, wc2)
        WCHUNK(3, T, wc3)
        #pragma unroll
        for (int r = 0; r < 4; ++r) {
            const int rw = gq * 4 + r;
            const int col = T * 16 + cl;
            B4[rw * 136 + col] = bf16rne(INV_SQ2f * wc2[r] * bf2f(B1[rw * 136 + col]));
            const float gt = bf2f(B2[rw * 136 + col]);
            B3[rw * 136 + col] = bf16rne(INV_SQ2f * wc3[r] * gt * y0f[rw]);
        }
    }
#undef WCHUNK
    CFENCE();

    // ---- G2: t = a2(B4) @ Wl1[0:128] -> tacc ----
    f32x4 tacc[8] = {Z4, Z4, Z4, Z4, Z4, Z4, Z4, Z4};
    #pragma unroll
    for (int ks = 0; ks < 4; ++ks) {
        const s16x8 a = ldA136(B4, cl, ks, gq);
        #pragma unroll
        for (int T = 0; T < 8; ++T)
            tacc[T] = MFMA16(a, ldB(wsb, 216 + T * 8 + ks, lane), tacc[T]);
    }
    CFENCE();   // G2 reads of B4 ordered before G3 stage overwrites B4

    // ---- G3: per component i: stage bv->B1 (os dead), gv->B4 (a2 dead),
    //      GEMM, store msg1 component i immediately ----
    #pragma unroll
    for (int i = 0; i < 3; ++i) {
        {
            const int dbase = (lane >> 2) * 68 + (lane & 3) * 16;
            const unsigned int* bD = (const unsigned int*)B3;
            const unsigned int* gD = (const unsigned int*)B2;
            unsigned int* o1 = (unsigned int*)B1;
            unsigned int* o4 = (unsigned int*)B4;
            #pragma unroll
            for (int jp = 0; jp < 16; ++jp) {
                const unsigned int bd = bD[dbase + jp];
                const unsigned int gd = gD[dbase + jp];
                const float v0 = bf2f((unsigned short)(vpack[i][jp] & 0xffff));
                const float v1 = bf2f((unsigned short)(vpack[i][jp] >> 16));
                o1[dbase + jp] = packbf(bf2f((unsigned short)(bd & 0xffff)) * v0,
                                        bf2f((unsigned short)(bd >> 16)) * v1);
                o4[dbase + jp] = packbf(bf2f((unsigned short)(gd & 0xffff)) * v0,
                                        bf2f((unsigned short)(gd >> 16)) * v1);
            }
        }
        CFENCE();   // uint stage writes -> s16x8 GEMM reads (TBAA hazard)
        f32x4 a3[8] = {Z4, Z4, Z4, Z4, Z4, Z4, Z4, Z4};
        #pragma unroll
        for (int ks = 0; ks < 4; ++ks) {
            const s16x8 a1 = ldA136(B1, cl, ks, gq);
            const s16x8 ag = ldA136(B4, cl, ks, gq);
            #pragma unroll
            for (int T = 0; T < 8; ++T) {
                a3[T] = MFMA16(a1, ldB(wsb, 216 + T * 8 + 4 + ks, lane), a3[T]);
                a3[T] = MFMA16(ag, ldB(wsb, 280 + T * 4 + ks, lane), a3[T]);
            }
        }
        CFENCE();   // GEMM reads ordered before next iteration's stage writes
        #pragma unroll
        for (int T = 0; T < 8; ++T)
            #pragma unroll
            for (int r = 0; r < 4; ++r) {
                const int rw = gq * 4 + r;
                const int col = T * 16 + cl;
                const size_t o = (size_t)(n0 + rw) * 512 + 128 + (size_t)col * 3 + i;
                OUT[o] = a3[T][r] + tacc[T][r] * y1f[rw * 3 + i] + SCp[o];
            }
    }
}

extern "C" void kernel_launch(void* const* d_in, const int* in_sizes, int n_in,
                              void* d_out, int out_size, void* d_ws, size_t ws_size,
                              hipStream_t stream)
{
    (void)in_sizes; (void)n_in; (void)out_size; (void)ws_size;
    const float* Sin  = (const float*)d_in[0];
    const float* Vin  = (const float*)d_in[1];
    const float* SCp  = (const float*)d_in[2];
    const float* ATT  = (const float*)d_in[3];
    const float* INVF = (const float*)d_in[4];
    const float* MNA  = (const float*)d_in[5];
    const float* MLEN = (const float*)d_in[6];
    const float* WSp  = (const float*)d_in[7];
    const float* WVp  = (const float*)d_in[8];
    const float* WC1  = (const float*)d_in[9];
    const float* WC2  = (const float*)d_in[10];
    const float* WC3  = (const float*)d_in[11];
    const float* WC4  = (const float*)d_in[12];
    const float* WB1  = (const float*)d_in[13];
    const float* WB2  = (const float*)d_in[14];
    const float* WB3  = (const float*)d_in[15];
    const float* WB4  = (const float*)d_in[16];
    const float* ESC  = (const float*)d_in[17];
    const float* WL0  = (const float*)d_in[18];
    const float* WL1  = (const float*)d_in[19];
    const float* WO0  = (const float*)d_in[20];
    const float* WO1  = (const float*)d_in[21];
    float* OUT = (float*)d_out;

    unsigned short* wsb = (unsigned short*)d_ws;
    hipLaunchKernelGGL(prep_frags, dim3(WS_FRAGS), dim3(64), 0, stream,
                       WC1, WC2, WC3, WB1, WB2, WB3, WC4, WB4,
                       WL0, WO0, WL1, WO1, wsb);
    // dynamic LDS: 4 buffers [16][136] (4352 B) + smalls (320 B) = 17728 B
    // -> ~8-9 one-wave blocks resident per CU, zero barriers per block.
    const size_t shbytes = (size_t)(4 * 4352 + 320);
    hipLaunchKernelGGL(epb_wave, dim3(NNODES / BN), dim3(NT), shbytes, stream,
                       Sin, Vin, SCp, ATT, INVF, MNA, MLEN, WSp, WVp, ESC,
                       wsb, OUT);
}

// Round 14
// 168.297 us; speedup vs baseline: 2.2086x; 2.2086x over previous
//
#include <hip/hip_runtime.h>

#define NNODES 65536
#define CC 128
#define NEL 10
#define BN 32
#define NT 256

#define INV_SQ2f 0.70710678118654752440f
#define INV_SQ6f 0.40824829046386301637f
#define INV_2Cf  0.0625f               /* 1/sqrt(256) */
#define INV_Cf   0.08838834764831845f  /* 1/sqrt(128) */
#define S16f 0.25f
#define S64f 0.125f

#define WS_FRAGS 312

typedef __attribute__((ext_vector_type(8))) short s16x8;
typedef __attribute__((ext_vector_type(4))) float f32x4;
#define MFMA16(a, b, c) __builtin_amdgcn_mfma_f32_16x16x32_bf16((a), (b), (c), 0, 0, 0)

union U8 { unsigned short u[8]; s16x8 s; };

__device__ __forceinline__ unsigned short bf16rne(float x) {
    unsigned int u = __float_as_uint(x);
    return (unsigned short)((u + 0x7FFFu + ((u >> 16) & 1u)) >> 16);
}
__device__ __forceinline__ float bf2f(unsigned short h) {
    return __uint_as_float(((unsigned int)h) << 16);
}
__device__ __forceinline__ unsigned int packbf(float a, float b) {
    return (unsigned int)bf16rne(a) | (((unsigned int)bf16rne(b)) << 16);
}
__device__ __forceinline__ float siluf(float x) {
    return x * (1.0f / (1.0f + __expf(-x)));
}

// ---------------- weight fragment prep (one-shot, 312 frags) ----------------
extern "C" __global__ void prep_frags(
    const float* __restrict__ WC1, const float* __restrict__ WC2,
    const float* __restrict__ WC3, const float* __restrict__ WB1,
    const float* __restrict__ WB2, const float* __restrict__ WB3,
    const float* __restrict__ WC4, const float* __restrict__ WB4,
    const float* __restrict__ WL0, const float* __restrict__ WO0,
    const float* __restrict__ WL1, const float* __restrict__ WO1,
    unsigned short* __restrict__ wsb)
{
    const int b = blockIdx.x;
    const int l = threadIdx.x;
    const float* W; int K, N, nKS, base; float sc;
    if      (b <  4) { W = WC1; K = 16;  N = 64;  nKS = 1; base = 0;   sc = S16f; }
    else if (b < 12) { W = WC2; K = 64;  N = 64;  nKS = 2; base = 4;   sc = S64f; }
    else if (b < 20) { W = WC3; K = 64;  N = 64;  nKS = 2; base = 12;  sc = S64f; }
    else if (b < 24) { W = WB1; K = 16;  N = 64;  nKS = 1; base = 20;  sc = S16f; }
    else if (b < 32) { W = WB2; K = 64;  N = 64;  nKS = 2; base = 24;  sc = S64f; }
    else if (b < 40) { W = WB3; K = 64;  N = 64;  nKS = 2; base = 32;  sc = S64f; }
    else if (b < 104){ W = WC4; K = 64;  N = 512; nKS = 2; base = 40;  sc = S64f; }
    else if (b < 120){ W = WB4; K = 64;  N = 128; nKS = 2; base = 104; sc = S64f; }
    else if (b < 184){ W = WL0; K = 256; N = 128; nKS = 8; base = 120; sc = INV_2Cf; }
    else if (b < 216){ W = WO0; K = 128; N = 128; nKS = 4; base = 184; sc = INV_Cf; }
    else if (b < 280){ W = WL1; K = 256; N = 128; nKS = 8; base = 216; sc = INV_2Cf; }
    else             { W = WO1; K = 128; N = 128; nKS = 4; base = 280; sc = INV_Cf; }
    const int f  = b - base;
    const int nt = f / nKS, ks = f % nKS;
    const int n  = nt * 16 + (l & 15);
    const int k0 = ks * 32 + (l >> 4) * 8;
    U8 v;
    #pragma unroll
    for (int j = 0; j < 8; ++j) {
        const int k = k0 + j;
        const float x = (k < K) ? W[(size_t)k * N + n] * sc : 0.0f;
        v.u[j] = bf16rne(x);
    }
    *(s16x8*)(wsb + (size_t)b * 512 + l * 8) = v.s;
}

// ---------------- helpers ----------------
__device__ __forceinline__ s16x8 ldB(const unsigned short* __restrict__ wsb, int fragidx, int lane) {
    return *(const s16x8*)(wsb + ((size_t)fragidx << 9) + lane * 8);
}
__device__ __forceinline__ s16x8 ldA136(const unsigned short* X, int row, int ks, int gq) {
    return *(const s16x8*)(X + row * 136 + ks * 32 + gq * 8);
}
__device__ __forceinline__ s16x8 ldA72(const unsigned short* X, int row, int ks, int gq) {
    return *(const s16x8*)(X + row * 72 + ks * 32 + gq * 8);
}

// ---------------- main fused MFMA kernel (R7 base) ----------------
// NT=256, 4 waves; wave w owns all 32 rows x its two 16-col tiles.
// R14 change vs R7: G1's msg0 accumulator stays in VGPRs; its SCp read and
// OUT store move to the final post-barrier epilogue. NO interval between
// barriers now contains any HBM op except P2's unavoidable input loads.
extern "C" __global__ void __launch_bounds__(NT)
epb_mfma(const float* __restrict__ Sin, const float* __restrict__ Vin,
         const float* __restrict__ SCp, const float* __restrict__ ATT,
         const float* __restrict__ INVF, const float* __restrict__ MNA,
         const float* __restrict__ MLEN, const float* __restrict__ WSp,
         const float* __restrict__ WVp, const float* __restrict__ ESC,
         const unsigned short* __restrict__ wsb, float* __restrict__ OUT)
{
    extern __shared__ char smem[];
    unsigned short* B1 = (unsigned short*)smem;          // Hc1 -> out_s -> bv(0,2)
    unsigned short* B2 = B1 + 4352;                      // Hb1 -> gate (persists)
    unsigned short* B3 = B2 + 4352;                      // Hc2 -> vy -> m1 -> gv(0,2)
    unsigned short* B4 = B3 + 4352;                      // Hb2 -> m0 -> bv(1)
    unsigned short* B5 = B4 + 4352;                      // Hc3 -> b (persists)
    unsigned short* B6 = B5 + 4352;                      // Hb3 -> a2 -> gv(1)
    float* y0f  = (float*)(smem + 6 * 8704);             // [32]
    float* y1f  = y0f + 32;                              // [32][3]
    float* etf  = y1f + 96;                              // [32]

    const int tid  = threadIdx.x;
    const int n0   = blockIdx.x * BN;
    const int w    = tid >> 6;
    const int lane = tid & 63;
    const int cl   = lane & 15;
    const int gq   = lane >> 4;
    const f32x4 Z4 = {0.f, 0.f, 0.f, 0.f};

    // ---- inv A-fragments (K=16 padded to 32) ----
    U8 invu[2];
    #pragma unroll
    for (int rg = 0; rg < 2; ++rg) {
        if (gq < 2) {
            const float* ip = INVF + (size_t)(n0 + rg * 16 + cl) * 16 + gq * 8;
            #pragma unroll
            for (int j = 0; j < 8; ++j) invu[rg].u[j] = bf16rne(ip[j]);
        } else {
            #pragma unroll
            for (int j = 0; j < 8; ++j) invu[rg].u[j] = 0;
        }
    }

    // ---- P0: per-node smalls ----
    if (tid < BN) {
        const int gn = n0 + tid;
        y0f[tid] = MNA[gn * 4 + 0];
        y1f[tid * 3 + 0] = MNA[gn * 4 + 1];
        y1f[tid * 3 + 1] = MNA[gn * 4 + 2];
        y1f[tid * 3 + 2] = MNA[gn * 4 + 3];
        etf[tid] = 1.0f - __expf(-ESC[0] * MLEN[gn]);
    }

    // ---- L1: inv @ WC1 -> B1, inv @ WB1 -> B2 ----
    #pragma unroll
    for (int rg = 0; rg < 2; ++rg) {
        const f32x4 c = MFMA16(invu[rg].s, ldB(wsb, 0 + w, lane), Z4);
        const f32x4 b = MFMA16(invu[rg].s, ldB(wsb, 20 + w, lane), Z4);
        #pragma unroll
        for (int r = 0; r < 4; ++r) {
            const int rw = rg * 16 + gq * 4 + r;
            B1[rw * 72 + w * 16 + cl] = bf16rne(siluf(c[r]));
            B2[rw * 72 + w * 16 + cl] = bf16rne(siluf(b[r]));
        }
    }
    __syncthreads();   // bar1

    // ---- L2: B1 -> B3 (WC2), B2 -> B4 (WB2) ----
    {
        f32x4 c[2] = {Z4, Z4}, b[2] = {Z4, Z4};
        #pragma unroll
        for (int ks = 0; ks < 2; ++ks) {
            const s16x8 fc = ldB(wsb, 4 + w * 2 + ks, lane);
            const s16x8 fb = ldB(wsb, 24 + w * 2 + ks, lane);
            #pragma unroll
            for (int rg = 0; rg < 2; ++rg) {
                c[rg] = MFMA16(ldA72(B1, rg * 16 + cl, ks, gq), fc, c[rg]);
                b[rg] = MFMA16(ldA72(B2, rg * 16 + cl, ks, gq), fb, b[rg]);
            }
        }
        #pragma unroll
        for (int rg = 0; rg < 2; ++rg)
            #pragma unroll
            for (int r = 0; r < 4; ++r) {
                const int rw = rg * 16 + gq * 4 + r;
                B3[rw * 72 + w * 16 + cl] = bf16rne(siluf(c[rg][r]));
                B4[rw * 72 + w * 16 + cl] = bf16rne(siluf(b[rg][r]));
            }
    }
    __syncthreads();   // bar2

    // ---- L3: B3 -> B5 (WC3), B4 -> B6 (WB3) ----
    {
        f32x4 c[2] = {Z4, Z4}, b[2] = {Z4, Z4};
        #pragma unroll
        for (int ks = 0; ks < 2; ++ks) {
            const s16x8 fc = ldB(wsb, 12 + w * 2 + ks, lane);
            const s16x8 fb = ldB(wsb, 32 + w * 2 + ks, lane);
            #pragma unroll
            for (int rg = 0; rg < 2; ++rg) {
                c[rg] = MFMA16(ldA72(B3, rg * 16 + cl, ks, gq), fc, c[rg]);
                b[rg] = MFMA16(ldA72(B4, rg * 16 + cl, ks, gq), fb, b[rg]);
            }
        }
        #pragma unroll
        for (int rg = 0; rg < 2; ++rg)
            #pragma unroll
            for (int r = 0; r < 4; ++r) {
                const int rw = rg * 16 + gq * 4 + r;
                B5[rw * 72 + w * 16 + cl] = bf16rne(siluf(c[rg][r]));
                B6[rw * 72 + w * 16 + cl] = bf16rne(siluf(b[rg][r]));
            }
    }
    __syncthreads();   // bar3

    // ---- h3 -> regs (from B5/B6); ob MFMAs ----
    s16x8 h3c[2][2], h3b[2][2];
    #pragma unroll
    for (int rg = 0; rg < 2; ++rg)
        #pragma unroll
        for (int ks = 0; ks < 2; ++ks) {
            h3c[rg][ks] = ldA72(B5, rg * 16 + cl, ks, gq);
            h3b[rg][ks] = ldA72(B6, rg * 16 + cl, ks, gq);
        }
    f32x4 obacc[2][2];
    #pragma unroll
    for (int tc = 0; tc < 2; ++tc) {
        const int T = w * 2 + tc;
        const s16x8 f0 = ldB(wsb, 104 + T * 2 + 0, lane);
        const s16x8 f1 = ldB(wsb, 104 + T * 2 + 1, lane);
        #pragma unroll
        for (int rg = 0; rg < 2; ++rg)
            obacc[rg][tc] = MFMA16(h3b[rg][1], f1, MFMA16(h3b[rg][0], f0, Z4));
    }

    // ---- P2 (same interval): out_s->B1, gate->B2, vy->B3 ----
    unsigned int vpack[3][8];
    {
        const int row = tid >> 3;
        const int c0  = (tid & 7) << 4;
        const size_t gn = (size_t)(n0 + row);
        const float4 mna = *(const float4*)(MNA + gn * 4);
        const float y10 = mna.y, y11 = mna.z, y12 = mna.w;
        int e = 0;
        #pragma unroll
        for (int k = 0; k < NEL; ++k)
            if (ATT[gn * NEL + k] > 0.5f) e = k;
        const float* sp  = Sin + gn * CC + c0;
        const float* vp  = Vin + (gn * CC + c0) * 3;
        const float* wsp = WSp + ((size_t)e * 5) * CC + c0;
        const float* wvp = WVp + ((size_t)e * 4) * CC + c0;
        unsigned int* B1d = (unsigned int*)B1;
        unsigned int* B2d = (unsigned int*)B2;
        unsigned int* B3d = (unsigned int*)B3;
        const int dbase = row * 68 + (c0 >> 1);
        #pragma unroll
        for (int jp = 0; jp < 8; ++jp) {
            const int c = 2 * jp;
            const float2 s2 = *(const float2*)(sp + c);
            const float2 va = *(const float2*)(vp + 3 * c);
            const float2 vb = *(const float2*)(vp + 3 * c + 2);
            const float2 vc = *(const float2*)(vp + 3 * c + 4);
            vpack[0][jp] = packbf(va.x, vb.y);
            vpack[1][jp] = packbf(va.y, vc.x);
            vpack[2][jp] = packbf(vb.x, vc.y);
            const float vv0 = va.x * va.x + va.y * va.y + vb.x * vb.x;
            const float vv1 = vb.y * vb.y + vc.x * vc.x + vc.y * vc.y;
            const float vy0 = va.x * y10 + va.y * y11 + vb.x * y12;
            const float vy1 = vb.y * y10 + vc.x * y11 + vc.y * y12;
            const float2 p0 = *(const float2*)(wsp + 0 * CC + c);
            const float2 p1 = *(const float2*)(wsp + 1 * CC + c);
            const float2 p2 = *(const float2*)(wsp + 2 * CC + c);
            const float2 p3 = *(const float2*)(wsp + 3 * CC + c);
            const float2 p4 = *(const float2*)(wsp + 4 * CC + c);
            const float2 q0 = *(const float2*)(wvp + 0 * CC + c);
            const float2 q1 = *(const float2*)(wvp + 1 * CC + c);
            const float2 q2 = *(const float2*)(wvp + 2 * CC + c);
            const float2 q3 = *(const float2*)(wvp + 3 * CC + c);
            const float s0 = s2.x, s1 = s2.y;
            const float ss0 = s0 * s0, ss1 = s1 * s1;
            const float os0 = p0.x * s0 + p1.x * ss0 + p2.x * vv0 + p3.x * (ss0 * s0) + p4.x * (s0 * vv0);
            const float os1 = p0.y * s1 + p1.y * ss1 + p2.y * vv1 + p3.y * (ss1 * s1) + p4.y * (s1 * vv1);
            const float gt0 = q0.x + q1.x * s0 + q2.x * ss0 + q3.x * vv0;
            const float gt1 = q0.y + q1.y * s1 + q2.y * ss1 + q3.y * vv1;
            B1d[dbase + jp] = packbf(os0, os1);
            B2d[dbase + jp] = packbf(gt0, gt1);
            B3d[dbase + jp] = packbf(vy0, vy1);
        }
    }
    __syncthreads();   // bar4

    // ---- m-phase (ONE interval): m0->B4, m1->B3(ip), a2->B6, b->B5 ----
#define WCHUNK(q, wc)                                                          \
    {                                                                          \
        _Pragma("unroll")                                                      \
        for (int tc = 0; tc < 2; ++tc) {                                       \
            const int T = w * 2 + tc;                                          \
            const s16x8 f0 = ldB(wsb, 40 + ((q) * 8 + T) * 2 + 0, lane);       \
            const s16x8 f1 = ldB(wsb, 40 + ((q) * 8 + T) * 2 + 1, lane);       \
            _Pragma("unroll")                                                  \
            for (int rg = 0; rg < 2; ++rg)                                     \
                wc[rg][tc] = MFMA16(h3c[rg][1], f1, MFMA16(h3c[rg][0], f0, Z4)); \
        }                                                                      \
    }
    {
        f32x4 wc[2][2];
        WCHUNK(0, wc)   // m0
        #pragma unroll
        for (int rg = 0; rg < 2; ++rg)
            #pragma unroll
            for (int tc = 0; tc < 2; ++tc)
                #pragma unroll
                for (int r = 0; r < 4; ++r) {
                    const int rw = rg * 16 + gq * 4 + r;
                    const int col = (w * 2 + tc) * 16 + cl;
                    const float os = bf2f(B1[rw * 136 + col]);
                    B4[rw * 136 + col] = bf16rne(INV_SQ2f * wc[rg][tc][r] * os * y0f[rw]
                                                 + etf[rw] * obacc[rg][tc][r]);
                }
        WCHUNK(1, wc)   // m1
        #pragma unroll
        for (int rg = 0; rg < 2; ++rg)
            #pragma unroll
            for (int tc = 0; tc < 2; ++tc)
                #pragma unroll
                for (int r = 0; r < 4; ++r) {
                    const int rw = rg * 16 + gq * 4 + r;
                    const int col = (w * 2 + tc) * 16 + cl;
                    const float gt = bf2f(B2[rw * 136 + col]);
                    const float vy = bf2f(B3[rw * 136 + col]);
                    B3[rw * 136 + col] = bf16rne(INV_SQ6f * wc[rg][tc][r] * gt * vy);
                }
        WCHUNK(2, wc)   // a2
        #pragma unroll
        for (int rg = 0; rg < 2; ++rg)
            #pragma unroll
            for (int tc = 0; tc < 2; ++tc)
                #pragma unroll
                for (int r = 0; r < 4; ++r) {
                    const int rw = rg * 16 + gq * 4 + r;
                    const int col = (w * 2 + tc) * 16 + cl;
                    B6[rw * 136 + col] = bf16rne(INV_SQ2f * wc[rg][tc][r] * bf2f(B1[rw * 136 + col]));
                }
        WCHUNK(3, wc)   // b
        #pragma unroll
        for (int rg = 0; rg < 2; ++rg)
            #pragma unroll
            for (int tc = 0; tc < 2; ++tc)
                #pragma unroll
                for (int r = 0; r < 4; ++r) {
                    const int rw = rg * 16 + gq * 4 + r;
                    const int col = (w * 2 + tc) * 16 + cl;
                    const float gt = bf2f(B2[rw * 136 + col]);
                    B5[rw * 136 + col] = bf16rne(INV_SQ2f * wc[rg][tc][r] * gt * y0f[rw]);
                }
    }
#undef WCHUNK
    __syncthreads();   // bar5

    // ---- G1 (msg0 -> REGS, no HBM) + G2 (t) in one interval ----
    f32x4 macc[2][2] = {{Z4, Z4}, {Z4, Z4}};   // msg0 accumulator, persists to epilogue
    f32x4 tacc[2][2] = {{Z4, Z4}, {Z4, Z4}};
    {
        #pragma unroll
        for (int ks = 0; ks < 12; ++ks) {
            const unsigned short* Xa = (ks < 4) ? B4 : (ks < 8) ? B3 : B1;
            s16x8 a[2];
            #pragma unroll
            for (int rg = 0; rg < 2; ++rg) a[rg] = ldA136(Xa, rg * 16 + cl, ks & 3, gq);
            #pragma unroll
            for (int tc = 0; tc < 2; ++tc) {
                const int T = w * 2 + tc;
                const int fi = (ks < 8) ? (120 + T * 8 + ks) : (184 + T * 4 + (ks - 8));
                const s16x8 bfrag = ldB(wsb, fi, lane);
                #pragma unroll
                for (int rg = 0; rg < 2; ++rg)
                    macc[rg][tc] = MFMA16(a[rg], bfrag, macc[rg][tc]);
            }
        }
        #pragma unroll
        for (int ks = 0; ks < 4; ++ks) {
            s16x8 a[2];
            #pragma unroll
            for (int rg = 0; rg < 2; ++rg) a[rg] = ldA136(B6, rg * 16 + cl, ks, gq);
            #pragma unroll
            for (int tc = 0; tc < 2; ++tc) {
                const s16x8 bfrag = ldB(wsb, 216 + (w * 2 + tc) * 8 + ks, lane);
                #pragma unroll
                for (int rg = 0; rg < 2; ++rg)
                    tacc[rg][tc] = MFMA16(a[rg], bfrag, tacc[rg][tc]);
            }
        }
    }
    __syncthreads();   // bar6: B1,B3,B4,B6 now dead

    // ---- G3: ping-pong staging (B1,B3)/(B4,B6); acc3 in regs ----
    f32x4 acc3[3][2][2];

#define STAGE_I(i, DSTB, DSTG)                                                  \
    {                                                                           \
        const int dbase = (tid >> 3) * 68 + (tid & 7) * 8;                      \
        const unsigned int* bD = (const unsigned int*)B5;                       \
        const unsigned int* gD = (const unsigned int*)B2;                       \
        unsigned int* o1 = (unsigned int*)(DSTB);                               \
        unsigned int* o3 = (unsigned int*)(DSTG);                               \
        _Pragma("unroll")                                                       \
        for (int jp = 0; jp < 8; ++jp) {                                        \
            const unsigned int bd = bD[dbase + jp];                             \
            const unsigned int gd = gD[dbase + jp];                             \
            const float v0 = bf2f((unsigned short)(vpack[i][jp] & 0xffff));     \
            const float v1 = bf2f((unsigned short)(vpack[i][jp] >> 16));        \
            o1[dbase + jp] = packbf(bf2f((unsigned short)(bd & 0xffff)) * v0,   \
                                    bf2f((unsigned short)(bd >> 16)) * v1);     \
            o3[dbase + jp] = packbf(bf2f((unsigned short)(gd & 0xffff)) * v0,   \
                                    bf2f((unsigned short)(gd >> 16)) * v1);     \
        }                                                                       \
    }

#define GEMM_I(i, SRCB, SRCG)                                                   \
    {                                                                           \
        _Pragma("unroll")                                                       \
        for (int rg = 0; rg < 2; ++rg)                                          \
            _Pragma("unroll")                                                   \
            for (int tc = 0; tc < 2; ++tc) acc3[i][rg][tc] = Z4;                \
        _Pragma("unroll")                                                       \
        for (int ks = 0; ks < 4; ++ks) {                                        \
            s16x8 a1[2], a3[2];                                                 \
            _Pragma("unroll")                                                   \
            for (int rg = 0; rg < 2; ++rg) {                                    \
                a1[rg] = ldA136((SRCB), rg * 16 + cl, ks, gq);                  \
                a3[rg] = ldA136((SRCG), rg * 16 + cl, ks, gq);                  \
            }                                                                   \
            _Pragma("unroll")                                                   \
            for (int tc = 0; tc < 2; ++tc) {                                    \
                const int T = w * 2 + tc;                                       \
                const s16x8 fb = ldB(wsb, 216 + T * 8 + 4 + ks, lane);          \
                const s16x8 fg = ldB(wsb, 280 + T * 4 + ks, lane);              \
                _Pragma("unroll")                                               \
                for (int rg = 0; rg < 2; ++rg) {                                \
                    acc3[i][rg][tc] = MFMA16(a1[rg], fb, acc3[i][rg][tc]);      \
                    acc3[i][rg][tc] = MFMA16(a3[rg], fg, acc3[i][rg][tc]);      \
                }                                                               \
            }                                                                   \
        }                                                                       \
    }

    STAGE_I(0, B1, B3)
    __syncthreads();   // bar7
    GEMM_I(0, B1, B3)
    STAGE_I(1, B4, B6)
    __syncthreads();   // bar8
    GEMM_I(1, B4, B6)
    STAGE_I(2, B1, B3)
    __syncthreads();   // bar9 (last barrier)
    GEMM_I(2, B1, B3)

    // ---- final epilogue AFTER last barrier: ALL HBM epilogue ops here ----
    // msg0 = macc + sc
    #pragma unroll
    for (int rg = 0; rg < 2; ++rg)
        #pragma unroll
        for (int tc = 0; tc < 2; ++tc)
            #pragma unroll
            for (int r = 0; r < 4; ++r) {
                const int rw = rg * 16 + gq * 4 + r;
                const size_t o = (size_t)(n0 + rw) * 512 + (w * 2 + tc) * 16 + cl;
                OUT[o] = macc[rg][tc][r] + SCp[o];
            }
    // msg1 = acc3 + t*y1 + sc (contiguous 12B per (rg,tc,r))
    #pragma unroll
    for (int rg = 0; rg < 2; ++rg)
        #pragma unroll
        for (int tc = 0; tc < 2; ++tc)
            #pragma unroll
            for (int r = 0; r < 4; ++r) {
                const int rw = rg * 16 + gq * 4 + r;
                const int col = (w * 2 + tc) * 16 + cl;
                const size_t o = (size_t)(n0 + rw) * 512 + 128 + (size_t)col * 3;
                const float tv = tacc[rg][tc][r];
                OUT[o + 0] = acc3[0][rg][tc][r] + tv * y1f[rw * 3 + 0] + SCp[o + 0];
                OUT[o + 1] = acc3[1][rg][tc][r] + tv * y1f[rw * 3 + 1] + SCp[o + 1];
                OUT[o + 2] = acc3[2][rg][tc][r] + tv * y1f[rw * 3 + 2] + SCp[o + 2];
            }
#undef STAGE_I
#undef GEMM_I
}

extern "C" void kernel_launch(void* const* d_in, const int* in_sizes, int n_in,
                              void* d_out, int out_size, void* d_ws, size_t ws_size,
                              hipStream_t stream)
{
    (void)in_sizes; (void)n_in; (void)out_size; (void)ws_size;
    const float* Sin  = (const float*)d_in[0];
    const float* Vin  = (const float*)d_in[1];
    const float* SCp  = (const float*)d_in[2];
    const float* ATT  = (const float*)d_in[3];
    const float* INVF = (const float*)d_in[4];
    const float* MNA  = (const float*)d_in[5];
    const float* MLEN = (const float*)d_in[6];
    const float* WSp  = (const float*)d_in[7];
    const float* WVp  = (const float*)d_in[8];
    const float* WC1  = (const float*)d_in[9];
    const float* WC2  = (const float*)d_in[10];
    const float* WC3  = (const float*)d_in[11];
    const float* WC4  = (const float*)d_in[12];
    const float* WB1  = (const float*)d_in[13];
    const float* WB2  = (const float*)d_in[14];
    const float* WB3  = (const float*)d_in[15];
    const float* WB4  = (const float*)d_in[16];
    const float* ESC  = (const float*)d_in[17];
    const float* WL0  = (const float*)d_in[18];
    const float* WL1  = (const float*)d_in[19];
    const float* WO0  = (const float*)d_in[20];
    const float* WO1  = (const float*)d_in[21];
    float* OUT = (float*)d_out;

    unsigned short* wsb = (unsigned short*)d_ws;
    hipLaunchKernelGGL(prep_frags, dim3(WS_FRAGS), dim3(64), 0, stream,
                       WC1, WC2, WC3, WB1, WB2, WB3, WC4, WB4,
                       WL0, WO0, WL1, WO1, wsb);
    // dynamic LDS: 6 buffers (8704 B) + smalls (640 B) = 52864 B -> 3 blocks/CU
    const size_t shbytes = (size_t)(6 * 8704 + 640);
    hipLaunchKernelGGL(epb_mfma, dim3(NNODES / BN), dim3(NT), shbytes, stream,
                       Sin, Vin, SCp, ATT, INVF, MNA, MLEN, WSp, WVp, ESC,
                       wsb, OUT);
}

// Round 15
// 163.561 us; speedup vs baseline: 2.2726x; 1.0290x over previous
//
#include <hip/hip_runtime.h>

#define NNODES 65536
#define CC 128
#define NEL 10
#define BN 32
#define NT 256

#define INV_SQ2f 0.70710678118654752440f
#define INV_SQ6f 0.40824829046386301637f
#define INV_2Cf  0.0625f               /* 1/sqrt(256) */
#define INV_Cf   0.08838834764831845f  /* 1/sqrt(128) */
#define S16f 0.25f
#define S64f 0.125f

#define WS_FRAGS 312
#define WS_BYTES (WS_FRAGS * 1024)

typedef __attribute__((ext_vector_type(8))) short s16x8;
typedef __attribute__((ext_vector_type(4))) float f32x4;
#define MFMA16(a, b, c) __builtin_amdgcn_mfma_f32_16x16x32_bf16((a), (b), (c), 0, 0, 0)

union U8 { unsigned short u[8]; s16x8 s; };

__device__ __forceinline__ unsigned short bf16rne(float x) {
    unsigned int u = __float_as_uint(x);
    return (unsigned short)((u + 0x7FFFu + ((u >> 16) & 1u)) >> 16);
}
__device__ __forceinline__ float bf2f(unsigned short h) {
    return __uint_as_float(((unsigned int)h) << 16);
}
__device__ __forceinline__ unsigned int packbf(float a, float b) {
    return (unsigned int)bf16rne(a) | (((unsigned int)bf16rne(b)) << 16);
}
__device__ __forceinline__ float siluf(float x) {
    return x * (1.0f / (1.0f + __expf(-x)));
}

// ---------------- weight fragment prep (one-shot, 312 frags) ----------------
extern "C" __global__ void prep_frags(
    const float* __restrict__ WC1, const float* __restrict__ WC2,
    const float* __restrict__ WC3, const float* __restrict__ WB1,
    const float* __restrict__ WB2, const float* __restrict__ WB3,
    const float* __restrict__ WC4, const float* __restrict__ WB4,
    const float* __restrict__ WL0, const float* __restrict__ WO0,
    const float* __restrict__ WL1, const float* __restrict__ WO1,
    unsigned short* __restrict__ wsb)
{
    const int b = blockIdx.x;
    const int l = threadIdx.x;
    const float* W; int K, N, nKS, base; float sc;
    if      (b <  4) { W = WC1; K = 16;  N = 64;  nKS = 1; base = 0;   sc = S16f; }
    else if (b < 12) { W = WC2; K = 64;  N = 64;  nKS = 2; base = 4;   sc = S64f; }
    else if (b < 20) { W = WC3; K = 64;  N = 64;  nKS = 2; base = 12;  sc = S64f; }
    else if (b < 24) { W = WB1; K = 16;  N = 64;  nKS = 1; base = 20;  sc = S16f; }
    else if (b < 32) { W = WB2; K = 64;  N = 64;  nKS = 2; base = 24;  sc = S64f; }
    else if (b < 40) { W = WB3; K = 64;  N = 64;  nKS = 2; base = 32;  sc = S64f; }
    else if (b < 104){ W = WC4; K = 64;  N = 512; nKS = 2; base = 40;  sc = S64f; }
    else if (b < 120){ W = WB4; K = 64;  N = 128; nKS = 2; base = 104; sc = S64f; }
    else if (b < 184){ W = WL0; K = 256; N = 128; nKS = 8; base = 120; sc = INV_2Cf; }
    else if (b < 216){ W = WO0; K = 128; N = 128; nKS = 4; base = 184; sc = INV_Cf; }
    else if (b < 280){ W = WL1; K = 256; N = 128; nKS = 8; base = 216; sc = INV_2Cf; }
    else             { W = WO1; K = 128; N = 128; nKS = 4; base = 280; sc = INV_Cf; }
    const int f  = b - base;
    const int nt = f / nKS, ks = f % nKS;
    const int n  = nt * 16 + (l & 15);
    const int k0 = ks * 32 + (l >> 4) * 8;
    U8 v;
    #pragma unroll
    for (int j = 0; j < 8; ++j) {
        const int k = k0 + j;
        const float x = (k < K) ? W[(size_t)k * N + n] * sc : 0.0f;
        v.u[j] = bf16rne(x);
    }
    *(s16x8*)(wsb + (size_t)b * 512 + l * 8) = v.s;
}

// ---------------- helpers ----------------
__device__ __forceinline__ s16x8 ldB(const unsigned short* __restrict__ wsb, int fragidx, int lane) {
    return *(const s16x8*)(wsb + ((size_t)fragidx << 9) + lane * 8);
}
__device__ __forceinline__ s16x8 ldA136(const unsigned short* X, int row, int ks, int gq) {
    return *(const s16x8*)(X + row * 136 + ks * 32 + gq * 8);
}
__device__ __forceinline__ s16x8 ldA72(const unsigned short* X, int row, int ks, int gq) {
    return *(const s16x8*)(X + row * 72 + ks * 32 + gq * 8);
}

// ---------------- main fused MFMA kernel ----------------
// NT=256, 4 waves; wave w owns all 32 rows x its column slice.
// Best-measured configuration (163.6 us): 12-barrier schedule, 6 LDS buffers,
// ALL msg1 stores + SCp reads after the last barrier so their HBM latency
// never feeds a vmcnt(0) barrier-drain; ping-pong G3 staging.
extern "C" __global__ void __launch_bounds__(NT)
epb_mfma(const float* __restrict__ Sin, const float* __restrict__ Vin,
         const float* __restrict__ SCp, const float* __restrict__ ATT,
         const float* __restrict__ INVF, const float* __restrict__ MNA,
         const float* __restrict__ MLEN, const float* __restrict__ WSp,
         const float* __restrict__ WVp, const float* __restrict__ ESC,
         const unsigned short* __restrict__ wsb, float* __restrict__ OUT)
{
    extern __shared__ char smem[];
    unsigned short* B1 = (unsigned short*)smem;          // Hc1/Hc3 -> out_s -> a2 -> bv(0,2)
    unsigned short* B2 = B1 + 4352;                      // Hb1/Hb3 -> gate (persists)
    unsigned short* B3 = B2 + 4352;                      // Hc2 -> vy -> m1 -> gv(0,2)
    unsigned short* B4 = B3 + 4352;                      // Hb2 -> m0 -> b (persists)
    unsigned short* B5 = B4 + 4352;                      // bv(1)
    unsigned short* B6 = B5 + 4352;                      // gv(1)
    float* y0f  = (float*)(smem + 6 * 8704);             // [32]
    float* y1f  = y0f + 32;                              // [32][3]
    float* etf  = y1f + 96;                              // [32]
    int*   eidx = (int*)(etf + 32);                      // [32]

    const int tid  = threadIdx.x;
    const int n0   = blockIdx.x * BN;
    const int w    = tid >> 6;
    const int lane = tid & 63;
    const int cl   = lane & 15;
    const int gq   = lane >> 4;
    const f32x4 Z4 = {0.f, 0.f, 0.f, 0.f};

    // ---- inv A-fragments (K=16 padded to 32) ----
    U8 invu[2];
    #pragma unroll
    for (int rg = 0; rg < 2; ++rg) {
        if (gq < 2) {
            const float* ip = INVF + (size_t)(n0 + rg * 16 + cl) * 16 + gq * 8;
            #pragma unroll
            for (int j = 0; j < 8; ++j) invu[rg].u[j] = bf16rne(ip[j]);
        } else {
            #pragma unroll
            for (int j = 0; j < 8; ++j) invu[rg].u[j] = 0;
        }
    }

    // ---- P0: per-node smalls ----
    if (tid < BN) {
        const int gn = n0 + tid;
        y0f[tid] = MNA[gn * 4 + 0];
        y1f[tid * 3 + 0] = MNA[gn * 4 + 1];
        y1f[tid * 3 + 1] = MNA[gn * 4 + 2];
        y1f[tid * 3 + 2] = MNA[gn * 4 + 3];
        etf[tid] = 1.0f - __expf(-ESC[0] * MLEN[gn]);
        int e = 0;
        #pragma unroll
        for (int k = 0; k < NEL; ++k)
            if (ATT[(size_t)gn * NEL + k] > 0.5f) e = k;
        eidx[tid] = e;
    }

    // ---- L1: inv @ WC1 -> B1, inv @ WB1 -> B2 ----
    #pragma unroll
    for (int rg = 0; rg < 2; ++rg) {
        const f32x4 c = MFMA16(invu[rg].s, ldB(wsb, 0 + w, lane), Z4);
        const f32x4 b = MFMA16(invu[rg].s, ldB(wsb, 20 + w, lane), Z4);
        #pragma unroll
        for (int r = 0; r < 4; ++r) {
            const int rw = rg * 16 + gq * 4 + r;
            B1[rw * 72 + w * 16 + cl] = bf16rne(siluf(c[r]));
            B2[rw * 72 + w * 16 + cl] = bf16rne(siluf(b[r]));
        }
    }
    __syncthreads();   // bar1

    // ---- L2: reads B1,B2 -> writes B3,B4 ----
    {
        f32x4 c[2] = {Z4, Z4}, b[2] = {Z4, Z4};
        #pragma unroll
        for (int ks = 0; ks < 2; ++ks) {
            const s16x8 fc = ldB(wsb, 4 + w * 2 + ks, lane);
            const s16x8 fb = ldB(wsb, 24 + w * 2 + ks, lane);
            #pragma unroll
            for (int rg = 0; rg < 2; ++rg) {
                c[rg] = MFMA16(ldA72(B1, rg * 16 + cl, ks, gq), fc, c[rg]);
                b[rg] = MFMA16(ldA72(B2, rg * 16 + cl, ks, gq), fb, b[rg]);
            }
        }
        #pragma unroll
        for (int rg = 0; rg < 2; ++rg)
            #pragma unroll
            for (int r = 0; r < 4; ++r) {
                const int rw = rg * 16 + gq * 4 + r;
                B3[rw * 72 + w * 16 + cl] = bf16rne(siluf(c[rg][r]));
                B4[rw * 72 + w * 16 + cl] = bf16rne(siluf(b[rg][r]));
            }
    }
    __syncthreads();   // bar2

    // ---- L3: reads B3,B4 -> writes B1,B2 ----
    {
        f32x4 c[2] = {Z4, Z4}, b[2] = {Z4, Z4};
        #pragma unroll
        for (int ks = 0; ks < 2; ++ks) {
            const s16x8 fc = ldB(wsb, 12 + w * 2 + ks, lane);
            const s16x8 fb = ldB(wsb, 32 + w * 2 + ks, lane);
            #pragma unroll
            for (int rg = 0; rg < 2; ++rg) {
                c[rg] = MFMA16(ldA72(B3, rg * 16 + cl, ks, gq), fc, c[rg]);
                b[rg] = MFMA16(ldA72(B4, rg * 16 + cl, ks, gq), fb, b[rg]);
            }
        }
        #pragma unroll
        for (int rg = 0; rg < 2; ++rg)
            #pragma unroll
            for (int r = 0; r < 4; ++r) {
                const int rw = rg * 16 + gq * 4 + r;
                B1[rw * 72 + w * 16 + cl] = bf16rne(siluf(c[rg][r]));
                B2[rw * 72 + w * 16 + cl] = bf16rne(siluf(b[rg][r]));
            }
    }
    __syncthreads();   // bar3

    // ---- h3 -> regs ----
    s16x8 h3c[2][2], h3b[2][2];
    #pragma unroll
    for (int rg = 0; rg < 2; ++rg)
        #pragma unroll
        for (int ks = 0; ks < 2; ++ks) {
            h3c[rg][ks] = ldA72(B1, rg * 16 + cl, ks, gq);
            h3b[rg][ks] = ldA72(B2, rg * 16 + cl, ks, gq);
        }
    __syncthreads();   // bar4: h3 reads done; B1/B2 free

    // ---- P2 phase: ob/wc0/wc1 MFMAs (reg-only) overlap the global loads ----
    f32x4 obacc[2][2], wc0[2][2], wc1[2][2];
    #pragma unroll
    for (int tc = 0; tc < 2; ++tc) {
        const int T = w * 2 + tc;
        const s16x8 f0 = ldB(wsb, 104 + T * 2 + 0, lane);
        const s16x8 f1 = ldB(wsb, 104 + T * 2 + 1, lane);
        const s16x8 a0 = ldB(wsb, 40 + (0 * 8 + T) * 2 + 0, lane);
        const s16x8 a1 = ldB(wsb, 40 + (0 * 8 + T) * 2 + 1, lane);
        const s16x8 b0 = ldB(wsb, 40 + (1 * 8 + T) * 2 + 0, lane);
        const s16x8 b1 = ldB(wsb, 40 + (1 * 8 + T) * 2 + 1, lane);
        #pragma unroll
        for (int rg = 0; rg < 2; ++rg) {
            obacc[rg][tc] = MFMA16(h3b[rg][1], f1, MFMA16(h3b[rg][0], f0, Z4));
            wc0[rg][tc]   = MFMA16(h3c[rg][1], a1, MFMA16(h3c[rg][0], a0, Z4));
            wc1[rg][tc]   = MFMA16(h3c[rg][1], b1, MFMA16(h3c[rg][0], b0, Z4));
        }
    }

    // ---- P2: out_s->B1, gate->B2, vy->B3 (bf16); v kept packed in regs ----
    unsigned int vpack[3][8];
    {
        const int row = tid >> 3;
        const int c0  = (tid & 7) << 4;
        const size_t gn = (size_t)(n0 + row);
        const int e = eidx[row];
        const float y10 = y1f[row * 3], y11 = y1f[row * 3 + 1], y12 = y1f[row * 3 + 2];
        const float* sp  = Sin + gn * CC + c0;
        const float* vp  = Vin + (gn * CC + c0) * 3;
        const float* wsp = WSp + ((size_t)e * 5) * CC + c0;
        const float* wvp = WVp + ((size_t)e * 4) * CC + c0;
        unsigned int* B1d = (unsigned int*)B1;
        unsigned int* B2d = (unsigned int*)B2;
        unsigned int* B3d = (unsigned int*)B3;
        const int dbase = row * 68 + (c0 >> 1);
        #pragma unroll
        for (int jp = 0; jp < 8; ++jp) {
            const int c = 2 * jp;
            const float2 s2 = *(const float2*)(sp + c);
            const float2 va = *(const float2*)(vp + 3 * c);
            const float2 vb = *(const float2*)(vp + 3 * c + 2);
            const float2 vc = *(const float2*)(vp + 3 * c + 4);
            vpack[0][jp] = packbf(va.x, vb.y);
            vpack[1][jp] = packbf(va.y, vc.x);
            vpack[2][jp] = packbf(vb.x, vc.y);
            const float vv0 = va.x * va.x + va.y * va.y + vb.x * vb.x;
            const float vv1 = vb.y * vb.y + vc.x * vc.x + vc.y * vc.y;
            const float vy0 = va.x * y10 + va.y * y11 + vb.x * y12;
            const float vy1 = vb.y * y10 + vc.x * y11 + vc.y * y12;
            const float2 p0 = *(const float2*)(wsp + 0 * CC + c);
            const float2 p1 = *(const float2*)(wsp + 1 * CC + c);
            const float2 p2 = *(const float2*)(wsp + 2 * CC + c);
            const float2 p3 = *(const float2*)(wsp + 3 * CC + c);
            const float2 p4 = *(const float2*)(wsp + 4 * CC + c);
            const float2 q0 = *(const float2*)(wvp + 0 * CC + c);
            const float2 q1 = *(const float2*)(wvp + 1 * CC + c);
            const float2 q2 = *(const float2*)(wvp + 2 * CC + c);
            const float2 q3 = *(const float2*)(wvp + 3 * CC + c);
            const float s0 = s2.x, s1 = s2.y;
            const float ss0 = s0 * s0, ss1 = s1 * s1;
            const float os0 = p0.x * s0 + p1.x * ss0 + p2.x * vv0 + p3.x * (ss0 * s0) + p4.x * (s0 * vv0);
            const float os1 = p0.y * s1 + p1.y * ss1 + p2.y * vv1 + p3.y * (ss1 * s1) + p4.y * (s1 * vv1);
            const float gt0 = q0.x + q1.x * s0 + q2.x * ss0 + q3.x * vv0;
            const float gt1 = q0.y + q1.y * s1 + q2.y * ss1 + q3.y * vv1;
            B1d[dbase + jp] = packbf(os0, os1);
            B2d[dbase + jp] = packbf(gt0, gt1);
            B3d[dbase + jp] = packbf(vy0, vy1);
        }
    }
    __syncthreads();   // bar5

    // ---- m-phase (elementwise only): m1 -> B3 in place, m0 -> B4 ----
    #pragma unroll
    for (int rg = 0; rg < 2; ++rg)
        #pragma unroll
        for (int tc = 0; tc < 2; ++tc)
            #pragma unroll
            for (int r = 0; r < 4; ++r) {
                const int rw = rg * 16 + gq * 4 + r;
                const int col = (w * 2 + tc) * 16 + cl;
                const float gt = bf2f(B2[rw * 136 + col]);
                const float vy = bf2f(B3[rw * 136 + col]);
                B3[rw * 136 + col] = bf16rne(INV_SQ6f * wc1[rg][tc][r] * gt * vy);
                const float os = bf2f(B1[rw * 136 + col]);
                const float m0 = INV_SQ2f * wc0[rg][tc][r] * os * y0f[rw] + etf[rw] * obacc[rg][tc][r];
                B4[rw * 136 + col] = bf16rne(m0);
            }
    __syncthreads();   // bar6

    // ---- G1: msg0 = [m0|m1|os] @ [Wl0a;Wl0b;Wo0] + sc ----
    {
        f32x4 acc[2][2] = {{Z4, Z4}, {Z4, Z4}};
        #pragma unroll
        for (int ks = 0; ks < 12; ++ks) {
            const unsigned short* Xa = (ks < 4) ? B4 : (ks < 8) ? B3 : B1;
            s16x8 a[2];
            #pragma unroll
            for (int rg = 0; rg < 2; ++rg) a[rg] = ldA136(Xa, rg * 16 + cl, ks & 3, gq);
            #pragma unroll
            for (int tc = 0; tc < 2; ++tc) {
                const int T = w * 2 + tc;
                const int fi = (ks < 8) ? (120 + T * 8 + ks) : (184 + T * 4 + (ks - 8));
                const s16x8 bfrag = ldB(wsb, fi, lane);
                #pragma unroll
                for (int rg = 0; rg < 2; ++rg)
                    acc[rg][tc] = MFMA16(a[rg], bfrag, acc[rg][tc]);
            }
        }
        #pragma unroll
        for (int rg = 0; rg < 2; ++rg)
            #pragma unroll
            for (int tc = 0; tc < 2; ++tc)
                #pragma unroll
                for (int r = 0; r < 4; ++r) {
                    const int rw = rg * 16 + gq * 4 + r;
                    const size_t o = (size_t)(n0 + rw) * 512 + (w * 2 + tc) * 16 + cl;
                    OUT[o] = acc[rg][tc][r] + SCp[o];
                }
    }
    __syncthreads();   // bar7

    // ---- phase8: a2 = INV_SQ2*w2*out_s (B1 in place); b -> B4 ----
    {
        f32x4 wc2[2][2], wc3[2][2];
        #pragma unroll
        for (int tc = 0; tc < 2; ++tc) {
            const int T = w * 2 + tc;
            const s16x8 a0 = ldB(wsb, 40 + (2 * 8 + T) * 2 + 0, lane);
            const s16x8 a1 = ldB(wsb, 40 + (2 * 8 + T) * 2 + 1, lane);
            const s16x8 b0 = ldB(wsb, 40 + (3 * 8 + T) * 2 + 0, lane);
            const s16x8 b1 = ldB(wsb, 40 + (3 * 8 + T) * 2 + 1, lane);
            #pragma unroll
            for (int rg = 0; rg < 2; ++rg) {
                wc2[rg][tc] = MFMA16(h3c[rg][1], a1, MFMA16(h3c[rg][0], a0, Z4));
                wc3[rg][tc] = MFMA16(h3c[rg][1], b1, MFMA16(h3c[rg][0], b0, Z4));
            }
        }
        #pragma unroll
        for (int rg = 0; rg < 2; ++rg)
            #pragma unroll
            for (int tc = 0; tc < 2; ++tc)
                #pragma unroll
                for (int r = 0; r < 4; ++r) {
                    const int rw = rg * 16 + gq * 4 + r;
                    const int col = (w * 2 + tc) * 16 + cl;
                    B1[rw * 136 + col] = bf16rne(INV_SQ2f * wc2[rg][tc][r] * bf2f(B1[rw * 136 + col]));
                    const float gt = bf2f(B2[rw * 136 + col]);
                    B4[rw * 136 + col] = bf16rne(INV_SQ2f * wc3[rg][tc][r] * gt * y0f[rw]);
                }
    }
    __syncthreads();   // bar8

    // ---- G2: t = a2 @ Wl1[0:128] -> tacc ----
    f32x4 tacc[2][2] = {{Z4, Z4}, {Z4, Z4}};
    #pragma unroll
    for (int ks = 0; ks < 4; ++ks) {
        s16x8 a[2];
        #pragma unroll
        for (int rg = 0; rg < 2; ++rg) a[rg] = ldA136(B1, rg * 16 + cl, ks, gq);
        #pragma unroll
        for (int tc = 0; tc < 2; ++tc) {
            const s16x8 bfrag = ldB(wsb, 216 + (w * 2 + tc) * 8 + ks, lane);
            #pragma unroll
            for (int rg = 0; rg < 2; ++rg)
                tacc[rg][tc] = MFMA16(a[rg], bfrag, tacc[rg][tc]);
        }
    }
    __syncthreads();   // bar9: B1/B3 free

    // ---- G3: ping-pong staging; acc3 kept in regs; stores deferred to end ----
    f32x4 acc3[3][2][2];

#define STAGE_I(i, DSTB, DSTG)                                                  \
    {                                                                           \
        const int dbase = (tid >> 3) * 68 + (tid & 7) * 8;                      \
        const unsigned int* bD = (const unsigned int*)B4;                       \
        const unsigned int* gD = (const unsigned int*)B2;                       \
        unsigned int* o1 = (unsigned int*)(DSTB);                               \
        unsigned int* o3 = (unsigned int*)(DSTG);                               \
        _Pragma("unroll")                                                       \
        for (int jp = 0; jp < 8; ++jp) {                                        \
            const unsigned int bd = bD[dbase + jp];                             \
            const unsigned int gd = gD[dbase + jp];                             \
            const float v0 = bf2f((unsigned short)(vpack[i][jp] & 0xffff));     \
            const float v1 = bf2f((unsigned short)(vpack[i][jp] >> 16));        \
            o1[dbase + jp] = packbf(bf2f((unsigned short)(bd & 0xffff)) * v0,   \
                                    bf2f((unsigned short)(bd >> 16)) * v1);     \
            o3[dbase + jp] = packbf(bf2f((unsigned short)(gd & 0xffff)) * v0,   \
                                    bf2f((unsigned short)(gd >> 16)) * v1);     \
        }                                                                       \
    }

#define GEMM_I(i, SRCB, SRCG)                                                   \
    {                                                                           \
        _Pragma("unroll")                                                       \
        for (int rg = 0; rg < 2; ++rg)                                          \
            _Pragma("unroll")                                                   \
            for (int tc = 0; tc < 2; ++tc) acc3[i][rg][tc] = Z4;                \
        _Pragma("unroll")                                                       \
        for (int ks = 0; ks < 4; ++ks) {                                        \
            s16x8 a1[2], a3[2];                                                 \
            _Pragma("unroll")                                                   \
            for (int rg = 0; rg < 2; ++rg) {                                    \
                a1[rg] = ldA136((SRCB), rg * 16 + cl, ks, gq);                  \
                a3[rg] = ldA136((SRCG), rg * 16 + cl, ks, gq);                  \
            }                                                                   \
            _Pragma("unroll")                                                   \
            for (int tc = 0; tc < 2; ++tc) {                                    \
                const int T = w * 2 + tc;                                       \
                const s16x8 fb = ldB(wsb, 216 + T * 8 + 4 + ks, lane);          \
                const s16x8 fg = ldB(wsb, 280 + T * 4 + ks, lane);              \
                _Pragma("unroll")                                               \
                for (int rg = 0; rg < 2; ++rg) {                                \
                    acc3[i][rg][tc] = MFMA16(a1[rg], fb, acc3[i][rg][tc]);      \
                    acc3[i][rg][tc] = MFMA16(a3[rg], fg, acc3[i][rg][tc]);      \
                }                                                               \
            }                                                                   \
        }                                                                       \
    }

    STAGE_I(0, B1, B3)
    __syncthreads();   // bar10
    GEMM_I(0, B1, B3)
    STAGE_I(1, B5, B6)
    __syncthreads();   // bar11
    GEMM_I(1, B5, B6)
    STAGE_I(2, B1, B3)
    __syncthreads();   // bar12 (last barrier)
    GEMM_I(2, B1, B3)

    // ---- final epilogue AFTER last barrier: msg1 = acc3 + t*y1 + sc ----
    // contiguous 12B per (rg,tc,r); waves retire independently, no drain.
    #pragma unroll
    for (int rg = 0; rg < 2; ++rg)
        #pragma unroll
        for (int tc = 0; tc < 2; ++tc)
            #pragma unroll
            for (int r = 0; r < 4; ++r) {
                const int rw = rg * 16 + gq * 4 + r;
                const int col = (w * 2 + tc) * 16 + cl;
                const size_t o = (size_t)(n0 + rw) * 512 + 128 + (size_t)col * 3;
                const float tv = tacc[rg][tc][r];
                OUT[o + 0] = acc3[0][rg][tc][r] + tv * y1f[rw * 3 + 0] + SCp[o + 0];
                OUT[o + 1] = acc3[1][rg][tc][r] + tv * y1f[rw * 3 + 1] + SCp[o + 1];
                OUT[o + 2] = acc3[2][rg][tc][r] + tv * y1f[rw * 3 + 2] + SCp[o + 2];
            }
#undef STAGE_I
#undef GEMM_I
}

extern "C" void kernel_launch(void* const* d_in, const int* in_sizes, int n_in,
                              void* d_out, int out_size, void* d_ws, size_t ws_size,
                              hipStream_t stream)
{
    (void)in_sizes; (void)n_in; (void)out_size; (void)ws_size;
    const float* Sin  = (const float*)d_in[0];
    const float* Vin  = (const float*)d_in[1];
    const float* SCp  = (const float*)d_in[2];
    const float* ATT  = (const float*)d_in[3];
    const float* INVF = (const float*)d_in[4];
    const float* MNA  = (const float*)d_in[5];
    const float* MLEN = (const float*)d_in[6];
    const float* WSp  = (const float*)d_in[7];
    const float* WVp  = (const float*)d_in[8];
    const float* WC1  = (const float*)d_in[9];
    const float* WC2  = (const float*)d_in[10];
    const float* WC3  = (const float*)d_in[11];
    const float* WC4  = (const float*)d_in[12];
    const float* WB1  = (const float*)d_in[13];
    const float* WB2  = (const float*)d_in[14];
    const float* WB3  = (const float*)d_in[15];
    const float* WB4  = (const float*)d_in[16];
    const float* ESC  = (const float*)d_in[17];
    const float* WL0  = (const float*)d_in[18];
    const float* WL1  = (const float*)d_in[19];
    const float* WO0  = (const float*)d_in[20];
    const float* WO1  = (const float*)d_in[21];
    float* OUT = (float*)d_out;

    unsigned short* wsb = (unsigned short*)d_ws;
    hipLaunchKernelGGL(prep_frags, dim3(WS_FRAGS), dim3(64), 0, stream,
                       WC1, WC2, WC3, WB1, WB2, WB3, WC4, WB4,
                       WL0, WO0, WL1, WO1, wsb);
    // dynamic LDS: 6 buffers (8704 B) + smalls (768 B) = 52992 B -> 3 blocks/CU
    const size_t shbytes = (size_t)(6 * 8704 + 768);
    hipLaunchKernelGGL(epb_mfma, dim3(NNODES / BN), dim3(NT), shbytes, stream,
                       Sin, Vin, SCp, ATT, INVF, MNA, MLEN, WSp, WVp, ESC,
                       wsb, OUT);
}